// Round 17
// baseline (737.510 us; speedup 1.0000x reference)
//
#include <hip/hip_runtime.h>
#include <math.h>

#define D 256
#define K 1024
#define NR 65536
#define ST_SIZE (NR * D)          // 16777216
#define LOSS_OFF ST_SIZE
#define IDX_OFF (ST_SIZE + 1)
#define BM 128
#define TPB 256
#define NCG 32
#define NBLK (NR / BM)            // 512
#define MARGIN 2e-3f
#define CAND_CAP 4096

// phase mask bits
#define PH_SWEEP 1
#define PH_RESC  2
#define PH_EPI   4
#define PH_NOFLG 8

typedef short bf16x8 __attribute__((ext_vector_type(8)));
typedef float f32x16 __attribute__((ext_vector_type(16)));

__device__ __forceinline__ unsigned f2bf(float f) {
    unsigned u = __float_as_uint(f);
    return (u + 0x7FFFu + ((u >> 16) & 1u)) >> 16;
}
__device__ __forceinline__ uint4 packB(float4 a, float4 b) {
    uint4 w;
    w.x = f2bf(-2.f * a.x) | (f2bf(-2.f * a.y) << 16);
    w.y = f2bf(-2.f * a.z) | (f2bf(-2.f * a.w) << 16);
    w.z = f2bf(-2.f * b.x) | (f2bf(-2.f * b.y) << 16);
    w.w = f2bf(-2.f * b.z) | (f2bf(-2.f * b.w) << 16);
    return w;
}
__device__ __forceinline__ float sq_nf(float x) {
    float s = x * x;
    asm volatile("" : "+v"(s));
    return s;
}
template <typename F>
__device__ __forceinline__ float np_sumsq256(F ld) {
    float tot[2];
    #pragma unroll
    for (int h = 0; h < 2; ++h) {
        const int base = h * 128;
        float r[8];
        #pragma unroll
        for (int j = 0; j < 8; ++j) r[j] = sq_nf(ld(base + j));
        for (int i = 8; i < 128; i += 8) {
            #pragma unroll
            for (int j = 0; j < 8; ++j) r[j] += sq_nf(ld(base + i + j));
        }
        tot[h] = ((r[0] + r[1]) + (r[2] + r[3])) + ((r[4] + r[5]) + (r[6] + r[7]));
    }
    return tot[0] + tot[1];
}

__global__ void prep_kernel(const float* __restrict__ emb,
                            unsigned short* __restrict__ pb,
                            float* __restrict__ se) {
    if (blockIdx.x < 128) {
        const int c  = blockIdx.x * 256 + threadIdx.x;
        const int cg = c >> 10, r = c & 1023;
        const int ks = r >> 6,  l = r & 63;
        const float4* s4 = (const float4*)(emb + (size_t)(cg * 32 + (l & 31)) * D
                                               + ks * 16 + (l >> 5) * 8);
        ((uint4*)pb)[c] = packB(s4[0], s4[1]);
    } else {
        const int k = (blockIdx.x - 128) * 256 + threadIdx.x;
        const float* row = emb + (size_t)k * D;
        se[k] = np_sumsq256([&](int i) { return row[i]; });
    }
}

// r12 engine, phase-masked. M=7 is the real kernel (bit-identical pipeline).
template<int M>
__device__ __forceinline__ void vq_impl(const float* __restrict__ inp,
        const float* __restrict__ emb, const unsigned short* __restrict__ pb,
        const float* __restrict__ se, float* __restrict__ out,
        double* __restrict__ lsum, unsigned* __restrict__ sink) {
    __shared__ __align__(16) unsigned short Bt[2][8192];
    __shared__ float se_s[K];
    __shared__ float sx_s[BM];
    __shared__ float rfin[BM];
    __shared__ unsigned cand[CAND_CAP];
    __shared__ float candsc[CAND_CAP];
    __shared__ unsigned bestd[BM];
    __shared__ unsigned bestc[BM];
    __shared__ int ncand;

    const int t   = threadIdx.x;
    const int ws  = t >> 6;
    const int l   = t & 63;
    const int col = l & 31;
    const int hi  = l >> 5;
    const int r0  = blockIdx.x * BM;
    unsigned probe = 0;

    #pragma unroll
    for (int i = 0; i < K / TPB; ++i) se_s[i * TPB + t] = se[i * TPB + t];
    if (t < BM) { bestd[t] = 0xFFFFFFFFu; bestc[t] = 0xFFFFFFFFu; }
    if (t == 0) ncand = 0;

    // ---- A fragments ----
    bf16x8 afr[16];
    {
        const float* xrow = inp + (size_t)(r0 + ws * 32 + col) * D;
        #pragma unroll
        for (int ks = 0; ks < 16; ++ks) {
            const float4* p4 = (const float4*)(xrow + ks * 16 + hi * 8);
            float4 a = p4[0], b = p4[1];
            bf16x8 v;
            v[0] = (short)f2bf(a.x); v[1] = (short)f2bf(a.y);
            v[2] = (short)f2bf(a.z); v[3] = (short)f2bf(a.w);
            v[4] = (short)f2bf(b.x); v[5] = (short)f2bf(b.y);
            v[6] = (short)f2bf(b.z); v[7] = (short)f2bf(b.w);
            afr[ks] = v;
        }
    }

    // ---- fused sx (numpy-pairwise-exact) ----
    {
        const int slot = t & 15, grp = t >> 4;
        const int j = slot & 7, h = slot >> 3;
        for (int p = 0; p < 8; ++p) {
            const int row = p * 16 + grp;
            const float* base = inp + (size_t)(r0 + row) * D + h * 128 + j;
            float s = sq_nf(base[0]);
            #pragma unroll
            for (int i = 1; i < 16; ++i) s += sq_nf(base[i * 8]);
            #pragma unroll
            for (int m = 1; m <= 8; m <<= 1) s += __shfl_xor(s, m);
            if (slot == 0) sx_s[row] = s;
        }
    }

    float rmin[16];
    #pragma unroll
    for (int i = 0; i < 16; ++i) rmin[i] = INFINITY;

    const uint4* src = (const uint4*)pb;

    if constexpr (M & PH_SWEEP) {
        {
            uint4* bt0 = (uint4*)&Bt[0][0];
            #pragma unroll
            for (int q = 0; q < 4; ++q) bt0[q * TPB + t] = src[q * TPB + t];
        }
        int cur = 0;
        for (int cg = 0; cg < NCG; ++cg) {
            __syncthreads();
            uint4 pf[4];
            const bool haspf = (cg + 1 < NCG);
            if (haspf) {
                #pragma unroll
                for (int q = 0; q < 4; ++q)
                    pf[q] = src[(size_t)(cg + 1) * 1024 + q * TPB + t];
            }
            const float sev = se_s[cg * 32 + col];
            f32x16 aE, aO;
            #pragma unroll
            for (int i = 0; i < 16; ++i) { aE[i] = sev; aO[i] = 0.f; }
            const bf16x8* bp = (const bf16x8*)&Bt[cur][0];
            #pragma unroll
            for (int ks = 0; ks < 16; ks += 2) {
                aE = __builtin_amdgcn_mfma_f32_32x32x16_bf16(afr[ks],     bp[ks * 64 + l],       aE, 0, 0, 0);
                aO = __builtin_amdgcn_mfma_f32_32x32x16_bf16(afr[ks + 1], bp[(ks + 1) * 64 + l], aO, 0, 0, 0);
            }
            float sc[16];
            #pragma unroll
            for (int i = 0; i < 16; ++i) sc[i] = aE[i] + aO[i];

            if constexpr (!(M & PH_NOFLG)) {
                #pragma unroll
                for (int i = 0; i < 16; ++i) rmin[i] = fminf(rmin[i], sc[i]);
                if ((cg & 1) == 0) {
                    #pragma unroll
                    for (int i = 0; i < 16; ++i) {
                        #pragma unroll
                        for (int m = 1; m < 32; m <<= 1)
                            rmin[i] = fminf(rmin[i], __shfl_xor(rmin[i], m));
                    }
                }
                #pragma unroll
                for (int i = 0; i < 16; ++i) {
                    if (sc[i] <= rmin[i] + MARGIN) {
                        const int row_local = ws * 32 + (i & 3) + 8 * (i >> 2) + 4 * hi;
                        const int p = atomicAdd(&ncand, 1);
                        if (p < CAND_CAP) {
                            cand[p]   = ((unsigned)row_local << 10) | (unsigned)(cg * 32 + col);
                            candsc[p] = sc[i];
                        }
                    }
                }
            } else {
                #pragma unroll
                for (int i = 0; i < 16; ++i) probe ^= __float_as_uint(sc[i]);  // keep MFMAs live
            }
            if (haspf) {
                uint4* bt = (uint4*)&Bt[cur ^ 1][0];
                #pragma unroll
                for (int q = 0; q < 4; ++q) bt[q * TPB + t] = pf[q];
            }
            cur ^= 1;
        }
        if constexpr (!(M & PH_NOFLG)) {
            #pragma unroll
            for (int i = 0; i < 16; ++i) {
                #pragma unroll
                for (int m = 1; m < 32; m <<= 1)
                    rmin[i] = fminf(rmin[i], __shfl_xor(rmin[i], m));
            }
            if (col == 0) {
                #pragma unroll
                for (int i = 0; i < 16; ++i)
                    rfin[ws * 32 + (i & 3) + 8 * (i >> 2) + 4 * hi] = rmin[i];
            }
        }
        __syncthreads();
    }

    if constexpr (M & PH_RESC) {
        int n = ncand; if (n > CAND_CAP) n = CAND_CAP;
        {
            const int qw = l >> 4, lq = l & 15;
            for (int ci = ws * 4 + qw; ci < n; ci += 16) {
                const unsigned uc = cand[ci];
                const int row_local = uc >> 10, code = uc & 1023;
                const float sc = candsc[ci];
                if (sc <= rfin[row_local] + MARGIN) {
                    const float4* xp = (const float4*)(inp + (size_t)(r0 + row_local) * D) + lq * 4;
                    const float4* ep = (const float4*)(emb + (size_t)code * D) + lq * 4;
                    float p = 0.f;
                    #pragma unroll
                    for (int q = 0; q < 4; ++q) {
                        float4 x = xp[q], e = ep[q];
                        p = fmaf(x.x, e.x, p);
                        p = fmaf(x.y, e.y, p);
                        p = fmaf(x.z, e.z, p);
                        p = fmaf(x.w, e.w, p);
                    }
                    #pragma unroll
                    for (int m = 1; m <= 8; m <<= 1) p += __shfl_xor(p, m);
                    const float tv = sx_s[row_local] + se_s[code];
                    const float d  = fmaf(-2.f, p, tv);
                    if (lq == 0) {
                        candsc[ci] = d;
                        atomicMin(&bestd[row_local], __float_as_uint(d));
                    }
                } else if (lq == 0) {
                    candsc[ci] = INFINITY;
                }
            }
        }
        __syncthreads();
        for (int ci = t; ci < n; ci += TPB) {
            const unsigned uc = cand[ci];
            if (__float_as_uint(candsc[ci]) == bestd[uc >> 10])
                atomicMin(&bestc[uc >> 10], uc & 1023u);
        }
        __syncthreads();
    }

    if constexpr (M & PH_EPI) {
        if (t < BM) out[IDX_OFF + r0 + t] = (float)bestc[t];
        {
            float4* out4 = (float4*)(out + (size_t)r0 * D);
            const float4* emb4 = (const float4*)emb;
            #pragma unroll
            for (int i = 0; i < (BM * D) / (4 * TPB); ++i) {
                const int e = i * TPB + t;
                const int row = e >> 6, c4 = e & 63;
                out4[e] = emb4[((size_t)bestc[row] << 6) + c4];
            }
        }
        if (t < 64) {
            double s = (double)__uint_as_float(bestd[t]) + (double)__uint_as_float(bestd[t + 64]);
            #pragma unroll
            for (int m = 1; m < 64; m <<= 1) s += __shfl_xor(s, m);
            if (t == 0) lsum[blockIdx.x] = s;
        }
    } else {
        // ---- probe sink: keep every computed value live (rule #17) ----
        __syncthreads();
        unsigned live = probe;
        #pragma unroll
        for (int ks = 0; ks < 16; ++ks)
            #pragma unroll
            for (int j = 0; j < 8; ++j)
                live ^= (unsigned)(unsigned short)afr[ks][j];
        live ^= __float_as_uint(sx_s[t & (BM - 1)]);
        live ^= __float_as_uint(se_s[t & (K - 1)]);
        if constexpr ((M & PH_SWEEP) && !(M & PH_NOFLG)) {
            live ^= (unsigned)ncand;
            live ^= cand[t & (CAND_CAP - 1)] ^ __float_as_uint(candsc[t & (CAND_CAP - 1)]);
            live ^= __float_as_uint(rfin[t & (BM - 1)]);
        }
        if constexpr (M & PH_RESC)
            live ^= bestd[t & (BM - 1)] ^ bestc[t & (BM - 1)];
        #pragma unroll
        for (int m = 1; m < 64; m <<= 1) live ^= __shfl_xor(live, m);
        if ((t & 63) == 0) atomicAdd(&sink[blockIdx.x & (NBLK - 1)], live);
    }
}

__global__ __launch_bounds__(TPB, 1)
void vq_main(const float* inp, const float* emb, const unsigned short* pb,
             const float* se, float* out, double* lsum, unsigned* sink) {
    vq_impl<PH_SWEEP | PH_RESC | PH_EPI>(inp, emb, pb, se, out, lsum, sink);
}
__global__ __launch_bounds__(TPB, 1)
void vq_probe_pre(const float* inp, const float* emb, const unsigned short* pb,
                  const float* se, float* out, double* lsum, unsigned* sink) {
    vq_impl<0>(inp, emb, pb, se, out, lsum, sink);
}
__global__ __launch_bounds__(TPB, 1)
void vq_probe_mma(const float* inp, const float* emb, const unsigned short* pb,
                  const float* se, float* out, double* lsum, unsigned* sink) {
    vq_impl<PH_SWEEP | PH_NOFLG>(inp, emb, pb, se, out, lsum, sink);
}
__global__ __launch_bounds__(TPB, 1)
void vq_probe_swp(const float* inp, const float* emb, const unsigned short* pb,
                  const float* se, float* out, double* lsum, unsigned* sink) {
    vq_impl<PH_SWEEP>(inp, emb, pb, se, out, lsum, sink);
}
__global__ __launch_bounds__(TPB, 1)
void vq_probe_rsc(const float* inp, const float* emb, const unsigned short* pb,
                  const float* se, float* out, double* lsum, unsigned* sink) {
    vq_impl<PH_SWEEP | PH_RESC>(inp, emb, pb, se, out, lsum, sink);
}

__global__ void fin_kernel(const double* __restrict__ lsum, float* __restrict__ out) {
    const int l = threadIdx.x;
    double s = 0.0;
    #pragma unroll
    for (int i = 0; i < NBLK / 64; ++i) s += lsum[l * (NBLK / 64) + i];
    #pragma unroll
    for (int m = 1; m < 64; m <<= 1) s += __shfl_xor(s, m);
    if (l == 0) out[LOSS_OFF] = (float)(1.25 * s / (double)ST_SIZE);
}

extern "C" void kernel_launch(void* const* d_in, const int* in_sizes, int n_in,
                              void* d_out, int out_size, void* d_ws, size_t ws_size,
                              hipStream_t stream) {
    const float* inp = (const float*)d_in[0];
    const float* emb = (const float*)d_in[1];
    float* out = (float*)d_out;
    unsigned short* pb = (unsigned short*)d_ws;               // 512 KB
    float*  se_ws      = (float*)((char*)d_ws + 524288);      //   4 KB
    double* lsum       = (double*)((char*)d_ws + 528384);     //   4 KB
    unsigned* sink     = (unsigned*)((char*)d_ws + 536576);   //   2 KB probe sink

    prep_kernel<<<132, 256, 0, stream>>>(emb, pb, se_ws);
    vq_main<<<NBLK, TPB, 0, stream>>>(inp, emb, pb, se_ws, out, lsum, sink);
    fin_kernel<<<1, 64, 0, stream>>>(lsum, out);
    // ---- diagnostic probes (write only to ws sink; d_out untouched) ----
    vq_probe_pre<<<NBLK, TPB, 0, stream>>>(inp, emb, pb, se_ws, out, lsum, sink);
    vq_probe_mma<<<NBLK, TPB, 0, stream>>>(inp, emb, pb, se_ws, out, lsum, sink);
    vq_probe_swp<<<NBLK, TPB, 0, stream>>>(inp, emb, pb, se_ws, out, lsum, sink);
    vq_probe_rsc<<<NBLK, TPB, 0, stream>>>(inp, emb, pb, se_ws, out, lsum, sink);
}

// Round 18
// 245.472 us; speedup vs baseline: 3.0045x; 3.0045x over previous
//
#include <hip/hip_runtime.h>
#include <math.h>

#define D 256
#define K 1024
#define NR 65536
#define ST_SIZE (NR * D)          // 16777216
#define LOSS_OFF ST_SIZE
#define IDX_OFF (ST_SIZE + 1)
#define BM 64
#define TPB 256
#define NRND 32                   // staging rounds, 2x 16-code tiles each
#define NBLK (NR / BM)            // 1024
#define MARGIN 2e-3f
#define CAND_CAP 2048

typedef short bf16x8 __attribute__((ext_vector_type(8)));
typedef float f32x4 __attribute__((ext_vector_type(4)));

// f32 -> bf16 RNE (bit-level)
__device__ __forceinline__ unsigned f2bf(float f) {
    unsigned u = __float_as_uint(f);
    return (u + 0x7FFFu + ((u >> 16) & 1u)) >> 16;
}
__device__ __forceinline__ uint4 packB(float4 a, float4 b) {
    uint4 w;
    w.x = f2bf(-2.f * a.x) | (f2bf(-2.f * a.y) << 16);
    w.y = f2bf(-2.f * a.z) | (f2bf(-2.f * a.w) << 16);
    w.z = f2bf(-2.f * b.x) | (f2bf(-2.f * b.y) << 16);
    w.w = f2bf(-2.f * b.z) | (f2bf(-2.f * b.w) << 16);
    return w;
}

// anti-contraction square (numpy-identical rounding: mul rounded alone)
__device__ __forceinline__ float sq_nf(float x) {
    float s = x * x;
    asm volatile("" : "+v"(s));
    return s;
}
// numpy pairwise sum of squares over 256 elements (bit-exact, validated r2-r17)
template <typename F>
__device__ __forceinline__ float np_sumsq256(F ld) {
    float tot[2];
    #pragma unroll
    for (int h = 0; h < 2; ++h) {
        const int base = h * 128;
        float r[8];
        #pragma unroll
        for (int j = 0; j < 8; ++j) r[j] = sq_nf(ld(base + j));
        for (int i = 8; i < 128; i += 8) {
            #pragma unroll
            for (int j = 0; j < 8; ++j) r[j] += sq_nf(ld(base + i + j));
        }
        tot[h] = ((r[0] + r[1]) + (r[2] + r[3])) + ((r[4] + r[5]) + (r[6] + r[7]));
    }
    return tot[0] + tot[1];
}

// prep: blocks 0..127 pack bf16(-2e) in 16x16x32 B-fragment order
//   chunk ci = (ct*8 + kb)*64 + l : lane l holds -2*e[ct*16+(l&15)][kb*32+(l>>4)*8 + j]
// blocks 128..131: se (numpy-pairwise ||e||^2)
__global__ void prep_kernel(const float* __restrict__ emb,
                            unsigned short* __restrict__ pb,
                            float* __restrict__ se) {
    if (blockIdx.x < 128) {
        const int c  = blockIdx.x * 256 + threadIdx.x;    // chunk id, 32768 total
        const int ct = c >> 9;                            // 16-code tile 0..63
        const int r  = c & 511;
        const int kb = r >> 6, l = r & 63;
        const float* srcp = emb + (size_t)(ct * 16 + (l & 15)) * D
                                + kb * 32 + (l >> 4) * 8;
        const float4* s4 = (const float4*)srcp;
        ((uint4*)pb)[c] = packB(s4[0], s4[1]);
    } else {
        const int k = (blockIdx.x - 128) * 256 + threadIdx.x;   // < 1024
        const float* row = emb + (size_t)k * D;
        se[k] = np_sumsq256([&](int i) { return row[i]; });
    }
}

// main: 16x16x32-shape single-sweep prune (low reg footprint -> 4 blocks/CU),
//       rfin filter + exact f32 rescore + two-phase select + st(=q) + loss
__global__ __launch_bounds__(TPB, 1)
void vq_main(const float* __restrict__ inp, const float* __restrict__ emb,
             const unsigned short* __restrict__ pb, const float* __restrict__ se,
             float* __restrict__ out, double* __restrict__ lsum) {
    __shared__ __align__(16) unsigned short Bt[2 * 4096];  // 16 KB: 2 tiles x 512 chunks
    __shared__ float se_s[K];                              //  4 KB
    __shared__ float sx_s[BM];                             // .25 KB
    __shared__ float rfin[BM];                             // .25 KB
    __shared__ unsigned cand[CAND_CAP];                    //  8 KB
    __shared__ float candsc[CAND_CAP];                     //  8 KB
    __shared__ unsigned bestd[BM];                         // .25 KB
    __shared__ unsigned bestc[BM];                         // .25 KB (~38 KB tot)
    __shared__ int ncand;

    const int t   = threadIdx.x;
    const int ws  = t >> 6;      // wave 0..3: rows ws*16 .. ws*16+15
    const int l   = t & 63;
    const int c16 = l & 15;      // A-row / B-col lane index
    const int g4  = l >> 4;      // k-group 0..3
    const int r0  = blockIdx.x * BM;

    #pragma unroll
    for (int i = 0; i < K / TPB; ++i) se_s[i * TPB + t] = se[i * TPB + t];
    if (t < BM) { bestd[t] = 0xFFFFFFFFu; bestc[t] = 0xFFFFFFFFu; }
    if (t == 0) ncand = 0;

    // ---- A fragments (32 VGPR): row r0+ws*16+c16, k = kb*32 + g4*8 + j ----
    bf16x8 afr[8];
    {
        const float* xrow = inp + (size_t)(r0 + ws * 16 + c16) * D;
        #pragma unroll
        for (int kb = 0; kb < 8; ++kb) {
            const float4* p4 = (const float4*)(xrow + kb * 32 + g4 * 8);
            float4 a = p4[0], b = p4[1];
            bf16x8 v;
            v[0] = (short)f2bf(a.x); v[1] = (short)f2bf(a.y);
            v[2] = (short)f2bf(a.z); v[3] = (short)f2bf(a.w);
            v[4] = (short)f2bf(b.x); v[5] = (short)f2bf(b.y);
            v[6] = (short)f2bf(b.z); v[7] = (short)f2bf(b.w);
            afr[kb] = v;
        }
    }

    // ---- fused sx: numpy-pairwise-exact, 16 lanes per row (pure shfl) ----
    {
        const int slot = t & 15, grp = t >> 4;   // 16 groups x 4 rows
        const int j = slot & 7, h = slot >> 3;
        #pragma unroll
        for (int p = 0; p < 4; ++p) {
            const int row = p * 16 + grp;
            const float* base = inp + (size_t)(r0 + row) * D + h * 128 + j;
            float s = sq_nf(base[0]);
            #pragma unroll
            for (int i = 1; i < 16; ++i) s += sq_nf(base[i * 8]);
            #pragma unroll
            for (int m = 1; m <= 8; m <<= 1) s += __shfl_xor(s, m);  // local-left
            if (slot == 0) sx_s[row] = s;
        }
    }

    float rmin[4];
    #pragma unroll
    for (int i = 0; i < 4; ++i) rmin[i] = INFINITY;

    const uint4* srcv = (const uint4*)pb;

    // ---- prologue: stage round 0 (2 tiles = 1024 chunks, coalesced) ----
    {
        uint4* btv = (uint4*)Bt;
        #pragma unroll
        for (int q = 0; q < 4; ++q) btv[q * TPB + t] = srcv[q * TPB + t];
    }

    // ---- single sweep: 32 rounds x {2 tiles x 8 MFMA}, r13-proven cadence ----
    for (int cr = 0; cr < NRND; ++cr) {
        __syncthreads();                       // Bt published (+ inits on cr=0)
        uint4 pf[4];
        const bool haspf = (cr + 1 < NRND);
        if (haspf) {
            #pragma unroll
            for (int q = 0; q < 4; ++q)
                pf[q] = srcv[(size_t)(cr + 1) * 1024 + q * TPB + t];
        }
        const bf16x8* bch = (const bf16x8*)Bt;
        f32x4 acc0, acc1;
        {
            const float sev0 = se_s[(cr * 2 + 0) * 16 + c16];
            const float sev1 = se_s[(cr * 2 + 1) * 16 + c16];
            #pragma unroll
            for (int i = 0; i < 4; ++i) { acc0[i] = sev0; acc1[i] = sev1; }
        }
        #pragma unroll
        for (int kb = 0; kb < 8; ++kb) {       // two independent acc chains
            acc0 = __builtin_amdgcn_mfma_f32_16x16x32_bf16(afr[kb], bch[kb * 64 + l],       acc0, 0, 0, 0);
            acc1 = __builtin_amdgcn_mfma_f32_16x16x32_bf16(afr[kb], bch[512 + kb * 64 + l], acc1, 0, 0, 0);
        }

        // running row-min: lane-local always; butterfly over the 16 cols
        // sharing each row every 2nd round (staleness raises threshold =>
        // flag set is a SUPERSET => argmin never lost; per-wave deterministic)
        #pragma unroll
        for (int i = 0; i < 4; ++i) rmin[i] = fminf(rmin[i], fminf(acc0[i], acc1[i]));
        if ((cr & 1) == 0) {
            #pragma unroll
            for (int i = 0; i < 4; ++i) {
                #pragma unroll
                for (int m = 1; m <= 8; m <<= 1)
                    rmin[i] = fminf(rmin[i], __shfl_xor(rmin[i], m));
            }
        }
        #pragma unroll
        for (int i = 0; i < 4; ++i) {
            const int row_local = ws * 16 + g4 * 4 + i;
            if (acc0[i] <= rmin[i] + MARGIN) {
                const int p = atomicAdd(&ncand, 1);
                if (p < CAND_CAP) {
                    cand[p]   = ((unsigned)row_local << 10) | (unsigned)((cr * 2) * 16 + c16);
                    candsc[p] = acc0[i];
                }
            }
            if (acc1[i] <= rmin[i] + MARGIN) {
                const int p = atomicAdd(&ncand, 1);
                if (p < CAND_CAP) {
                    cand[p]   = ((unsigned)row_local << 10) | (unsigned)((cr * 2 + 1) * 16 + c16);
                    candsc[p] = acc1[i];
                }
            }
        }
        __syncthreads();                       // all waves done reading Bt
        if (haspf) {
            uint4* btv = (uint4*)Bt;
            #pragma unroll
            for (int q = 0; q < 4; ++q) btv[q * TPB + t] = pf[q];
        }
    }
    // final butterfly -> exact per-row approx-min; publish for the filter
    #pragma unroll
    for (int i = 0; i < 4; ++i) {
        #pragma unroll
        for (int m = 1; m <= 8; m <<= 1)
            rmin[i] = fminf(rmin[i], __shfl_xor(rmin[i], m));
    }
    if (c16 == 0) {
        #pragma unroll
        for (int i = 0; i < 4; ++i)
            rfin[ws * 16 + g4 * 4 + i] = rmin[i];
    }
    __syncthreads();                               // cand list + rfin complete

    // ---- filter + exact f32 rescore: 16 lanes per candidate (r12-proven) ----
    int n = ncand; if (n > CAND_CAP) n = CAND_CAP;
    {
        const int qw = l >> 4, lq = l & 15;        // quarter-wave, lane-in-quarter
        for (int ci = ws * 4 + qw; ci < n; ci += 16) {
            const unsigned uc = cand[ci];
            const int row_local = uc >> 10, code = uc & 1023;
            const float sc = candsc[ci];
            if (sc <= rfin[row_local] + MARGIN) {  // survives final-min filter
                const float4* xp = (const float4*)(inp + (size_t)(r0 + row_local) * D) + lq * 4;
                const float4* ep = (const float4*)(emb + (size_t)code * D) + lq * 4;
                float p = 0.f;
                #pragma unroll
                for (int q = 0; q < 4; ++q) {
                    float4 x = xp[q], e = ep[q];
                    p = fmaf(x.x, e.x, p);
                    p = fmaf(x.y, e.y, p);
                    p = fmaf(x.z, e.z, p);
                    p = fmaf(x.w, e.w, p);
                }
                #pragma unroll
                for (int m = 1; m <= 8; m <<= 1) p += __shfl_xor(p, m);
                const float tv = sx_s[row_local] + se_s[code];
                const float d  = fmaf(-2.f, p, tv);    // = fl(t - 2*dot), matches numpy
                if (lq == 0) {
                    candsc[ci] = d;
                    atomicMin(&bestd[row_local], __float_as_uint(d));  // d>0: uint-monotone
                }
            } else if (lq == 0) {
                candsc[ci] = INFINITY;             // can't match bestd in phase 2
            }
        }
    }
    __syncthreads();
    for (int ci = t; ci < n; ci += TPB) {          // tie-break: lowest code at min d
        const unsigned uc = cand[ci];
        if (__float_as_uint(candsc[ci]) == bestd[uc >> 10])
            atomicMin(&bestc[uc >> 10], uc & 1023u);
    }
    __syncthreads();
    if (t < BM) out[IDX_OFF + r0 + t] = (float)bestc[t];

    // ---- st = q (r12-validated, |err| <= 6e-7 << thr): pure q-write ----
    {
        float4* out4 = (float4*)(out + (size_t)r0 * D);
        const float4* emb4 = (const float4*)emb;
        #pragma unroll
        for (int i = 0; i < (BM * D) / (4 * TPB); ++i) {   // 16 iters
            const int e = i * TPB + t;
            out4[e] = emb4[((size_t)bestc[e >> 6] << 6) + (e & 63)];
        }
    }

    // ---- loss partial: sum of winner distances (bestd) in f64, fixed tree ----
    if (t < 64) {
        double s = (double)__uint_as_float(bestd[t]);
        #pragma unroll
        for (int m = 1; m < 64; m <<= 1) s += __shfl_xor(s, m);
        if (t == 0) lsum[blockIdx.x] = s;
    }
}

// fin: loss = 1.25 * sum(d_winner) / (N*D); one wave, fixed-tree reduction
__global__ void fin_kernel(const double* __restrict__ lsum, float* __restrict__ out) {
    const int l = threadIdx.x;                     // 64 lanes
    double s = 0.0;
    #pragma unroll
    for (int i = 0; i < NBLK / 64; ++i) s += lsum[l * (NBLK / 64) + i];
    #pragma unroll
    for (int m = 1; m < 64; m <<= 1) s += __shfl_xor(s, m);
    if (l == 0) out[LOSS_OFF] = (float)(1.25 * s / (double)ST_SIZE);
}

extern "C" void kernel_launch(void* const* d_in, const int* in_sizes, int n_in,
                              void* d_out, int out_size, void* d_ws, size_t ws_size,
                              hipStream_t stream) {
    const float* inp = (const float*)d_in[0];
    const float* emb = (const float*)d_in[1];
    float* out = (float*)d_out;
    unsigned short* pb = (unsigned short*)d_ws;               // 512 KB (frag-ordered bf16)
    float*  se_ws      = (float*)((char*)d_ws + 524288);      //   4 KB
    double* lsum       = (double*)((char*)d_ws + 528384);     //   8 KB (1024 doubles)

    prep_kernel<<<132, 256, 0, stream>>>(emb, pb, se_ws);
    vq_main<<<NBLK, TPB, 0, stream>>>(inp, emb, pb, se_ws, out, lsum);
    fin_kernel<<<1, 64, 0, stream>>>(lsum, out);
}

// Round 19
// 174.132 us; speedup vs baseline: 4.2354x; 1.4097x over previous
//
#include <hip/hip_runtime.h>
#include <math.h>

#define D 256
#define K 1024
#define NR 65536
#define ST_SIZE (NR * D)          // 16777216
#define LOSS_OFF ST_SIZE
#define IDX_OFF (ST_SIZE + 1)
#define BM 64
#define TPB 256
#define NRND 32                   // staging rounds, 2x 16-code tiles each
#define NBLK (NR / BM)            // 1024
#define MARGIN 2e-3f
#define CAND_CAP 2048

typedef short bf16x8 __attribute__((ext_vector_type(8)));
typedef float f32x4 __attribute__((ext_vector_type(4)));

// async global->LDS, 16B per lane; LDS dest = wave-uniform base + lane*16
#define GLDS(g, s) __builtin_amdgcn_global_load_lds( \
    (const __attribute__((address_space(1))) unsigned int*)(g), \
    (__attribute__((address_space(3))) unsigned int*)(s), 16, 0, 0)

// f32 -> bf16 RNE (bit-level)
__device__ __forceinline__ unsigned f2bf(float f) {
    unsigned u = __float_as_uint(f);
    return (u + 0x7FFFu + ((u >> 16) & 1u)) >> 16;
}
__device__ __forceinline__ uint4 packB(float4 a, float4 b) {
    uint4 w;
    w.x = f2bf(-2.f * a.x) | (f2bf(-2.f * a.y) << 16);
    w.y = f2bf(-2.f * a.z) | (f2bf(-2.f * a.w) << 16);
    w.z = f2bf(-2.f * b.x) | (f2bf(-2.f * b.y) << 16);
    w.w = f2bf(-2.f * b.z) | (f2bf(-2.f * b.w) << 16);
    return w;
}

// anti-contraction square (numpy-identical rounding: mul rounded alone)
__device__ __forceinline__ float sq_nf(float x) {
    float s = x * x;
    asm volatile("" : "+v"(s));
    return s;
}
// numpy pairwise sum of squares over 256 elements (bit-exact, validated r2-r18)
template <typename F>
__device__ __forceinline__ float np_sumsq256(F ld) {
    float tot[2];
    #pragma unroll
    for (int h = 0; h < 2; ++h) {
        const int base = h * 128;
        float r[8];
        #pragma unroll
        for (int j = 0; j < 8; ++j) r[j] = sq_nf(ld(base + j));
        for (int i = 8; i < 128; i += 8) {
            #pragma unroll
            for (int j = 0; j < 8; ++j) r[j] += sq_nf(ld(base + i + j));
        }
        tot[h] = ((r[0] + r[1]) + (r[2] + r[3])) + ((r[4] + r[5]) + (r[6] + r[7]));
    }
    return tot[0] + tot[1];
}

// prep: blocks 0..127 pack bf16(-2e) in 16x16x32 B-fragment order (r18-proven)
//   chunk ci = (ct*8 + kb)*64 + l : lane l holds -2*e[ct*16+(l&15)][kb*32+(l>>4)*8 + j]
__global__ void prep_kernel(const float* __restrict__ emb,
                            unsigned short* __restrict__ pb,
                            float* __restrict__ se) {
    if (blockIdx.x < 128) {
        const int c  = blockIdx.x * 256 + threadIdx.x;    // chunk id, 32768 total
        const int ct = c >> 9;                            // 16-code tile 0..63
        const int r  = c & 511;
        const int kb = r >> 6, l = r & 63;
        const float* srcp = emb + (size_t)(ct * 16 + (l & 15)) * D
                                + kb * 32 + (l >> 4) * 8;
        const float4* s4 = (const float4*)srcp;
        ((uint4*)pb)[c] = packB(s4[0], s4[1]);
    } else {
        const int k = (blockIdx.x - 128) * 256 + threadIdx.x;   // < 1024
        const float* row = emb + (size_t)k * D;
        se[k] = np_sumsq256([&](int i) { return row[i]; });
    }
}

// main: 16x16x32 single-sweep prune, async gload_lds dbuf staging (1 barrier/round),
//       waves_per_eu(2,4) pins allocator to 128-reg budget (anti-spill)
__global__ __attribute__((amdgpu_waves_per_eu(2, 4))) __launch_bounds__(TPB)
void vq_main(const float* __restrict__ inp, const float* __restrict__ emb,
             const unsigned short* __restrict__ pb, const float* __restrict__ se,
             float* __restrict__ out, double* __restrict__ lsum) {
    __shared__ __align__(16) unsigned short Bt[2][8192];   // 2 x 16 KB dbuf
    __shared__ float se_s[K];                              //  4 KB
    __shared__ float sx_s[BM];                             // .25 KB
    __shared__ float rfin[BM];                             // .25 KB
    __shared__ unsigned cand[CAND_CAP];                    //  8 KB
    __shared__ float candsc[CAND_CAP];                     //  8 KB
    __shared__ unsigned bestd[BM];                         // .25 KB
    __shared__ unsigned bestc[BM];                         // .25 KB (~53 KB tot)
    __shared__ int ncand;

    const int t   = threadIdx.x;
    const int ws  = t >> 6;      // wave 0..3: rows ws*16 .. ws*16+15
    const int l   = t & 63;
    const int c16 = l & 15;      // A-row / B-col lane index
    const int g4  = l >> 4;      // k-group 0..3
    const int r0  = blockIdx.x * BM;

    #pragma unroll
    for (int i = 0; i < K / TPB; ++i) se_s[i * TPB + t] = se[i * TPB + t];
    if (t < BM) { bestd[t] = 0xFFFFFFFFu; bestc[t] = 0xFFFFFFFFu; }
    if (t == 0) ncand = 0;

    // ---- A fragments (32 VGPR): row r0+ws*16+c16, k = kb*32 + g4*8 + j ----
    bf16x8 afr[8];
    {
        const float* xrow = inp + (size_t)(r0 + ws * 16 + c16) * D;
        #pragma unroll
        for (int kb = 0; kb < 8; ++kb) {
            const float4* p4 = (const float4*)(xrow + kb * 32 + g4 * 8);
            float4 a = p4[0], b = p4[1];
            bf16x8 v;
            v[0] = (short)f2bf(a.x); v[1] = (short)f2bf(a.y);
            v[2] = (short)f2bf(a.z); v[3] = (short)f2bf(a.w);
            v[4] = (short)f2bf(b.x); v[5] = (short)f2bf(b.y);
            v[6] = (short)f2bf(b.z); v[7] = (short)f2bf(b.w);
            afr[kb] = v;
        }
    }

    // ---- fused sx: numpy-pairwise-exact, 16 lanes per row (pure shfl) ----
    {
        const int slot = t & 15, grp = t >> 4;   // 16 groups x 4 rows
        const int j = slot & 7, h = slot >> 3;
        #pragma unroll
        for (int p = 0; p < 4; ++p) {
            const int row = p * 16 + grp;
            const float* base = inp + (size_t)(r0 + row) * D + h * 128 + j;
            float s = sq_nf(base[0]);
            #pragma unroll
            for (int i = 1; i < 16; ++i) s += sq_nf(base[i * 8]);
            #pragma unroll
            for (int m = 1; m <= 8; m <<= 1) s += __shfl_xor(s, m);  // local-left
            if (slot == 0) sx_s[row] = s;
        }
    }

    float rmin[4];
    #pragma unroll
    for (int i = 0; i < 4; ++i) rmin[i] = INFINITY;

    const uint4* srcv = (const uint4*)pb;

    // async stage of round cr into buffer buf: 1024 chunks of 16B, linear order
    auto stage = [&](int buf, int cr) {
        const uint4* g = srcv + (size_t)cr * 1024;
        #pragma unroll
        for (int q = 0; q < 4; ++q) {
            char* lbase = (char*)&Bt[buf][0] + (q * 256 + ws * 64) * 16;  // wave-uniform
            GLDS(g + q * TPB + t, lbase);                                  // lane adds l*16
        }
    };

    stage(0, 0);
    int cur = 0;
    // ---- single sweep: 32 rounds x {2 tiles x 8 MFMA}; ONE barrier per round;
    //      next round's DMA flies under this round's MFMAs ----
    for (int cr = 0; cr < NRND; ++cr) {
        __syncthreads();                       // own DMA drained (vmcnt0) + all waves done prev
        if (cr + 1 < NRND) stage(cur ^ 1, cr + 1);
        const bf16x8* bch = (const bf16x8*)&Bt[cur][0];
        f32x4 acc0, acc1;
        {
            const float sev0 = se_s[(cr * 2 + 0) * 16 + c16];
            const float sev1 = se_s[(cr * 2 + 1) * 16 + c16];
            #pragma unroll
            for (int i = 0; i < 4; ++i) { acc0[i] = sev0; acc1[i] = sev1; }
        }
        #pragma unroll
        for (int kb = 0; kb < 8; ++kb) {       // two independent acc chains
            acc0 = __builtin_amdgcn_mfma_f32_16x16x32_bf16(afr[kb], bch[kb * 64 + l],       acc0, 0, 0, 0);
            acc1 = __builtin_amdgcn_mfma_f32_16x16x32_bf16(afr[kb], bch[512 + kb * 64 + l], acc1, 0, 0, 0);
        }

        // running row-min: lane-local always; 16-lane butterfly every 2nd round
        // (staleness only raises threshold => flag set SUPERSET => argmin kept)
        #pragma unroll
        for (int i = 0; i < 4; ++i) rmin[i] = fminf(rmin[i], fminf(acc0[i], acc1[i]));
        if ((cr & 1) == 0) {
            #pragma unroll
            for (int i = 0; i < 4; ++i) {
                #pragma unroll
                for (int m = 1; m <= 8; m <<= 1)
                    rmin[i] = fminf(rmin[i], __shfl_xor(rmin[i], m));
            }
        }
        #pragma unroll
        for (int i = 0; i < 4; ++i) {
            const int row_local = ws * 16 + g4 * 4 + i;
            if (acc0[i] <= rmin[i] + MARGIN) {
                const int p = atomicAdd(&ncand, 1);
                if (p < CAND_CAP) {
                    cand[p]   = ((unsigned)row_local << 10) | (unsigned)((cr * 2) * 16 + c16);
                    candsc[p] = acc0[i];
                }
            }
            if (acc1[i] <= rmin[i] + MARGIN) {
                const int p = atomicAdd(&ncand, 1);
                if (p < CAND_CAP) {
                    cand[p]   = ((unsigned)row_local << 10) | (unsigned)((cr * 2 + 1) * 16 + c16);
                    candsc[p] = acc1[i];
                }
            }
        }
        cur ^= 1;
    }
    // final butterfly -> exact per-row approx-min; publish for the filter
    #pragma unroll
    for (int i = 0; i < 4; ++i) {
        #pragma unroll
        for (int m = 1; m <= 8; m <<= 1)
            rmin[i] = fminf(rmin[i], __shfl_xor(rmin[i], m));
    }
    if (c16 == 0) {
        #pragma unroll
        for (int i = 0; i < 4; ++i)
            rfin[ws * 16 + g4 * 4 + i] = rmin[i];
    }
    __syncthreads();                               // cand list + rfin complete

    // ---- filter + exact f32 rescore: 16 lanes per candidate (proven) ----
    int n = ncand; if (n > CAND_CAP) n = CAND_CAP;
    {
        const int qw = l >> 4, lq = l & 15;        // quarter-wave, lane-in-quarter
        for (int ci = ws * 4 + qw; ci < n; ci += 16) {
            const unsigned uc = cand[ci];
            const int row_local = uc >> 10, code = uc & 1023;
            const float sc = candsc[ci];
            if (sc <= rfin[row_local] + MARGIN) {  // survives final-min filter
                const float4* xp = (const float4*)(inp + (size_t)(r0 + row_local) * D) + lq * 4;
                const float4* ep = (const float4*)(emb + (size_t)code * D) + lq * 4;
                float p = 0.f;
                #pragma unroll
                for (int q = 0; q < 4; ++q) {
                    float4 x = xp[q], e = ep[q];
                    p = fmaf(x.x, e.x, p);
                    p = fmaf(x.y, e.y, p);
                    p = fmaf(x.z, e.z, p);
                    p = fmaf(x.w, e.w, p);
                }
                #pragma unroll
                for (int m = 1; m <= 8; m <<= 1) p += __shfl_xor(p, m);
                const float tv = sx_s[row_local] + se_s[code];
                const float d  = fmaf(-2.f, p, tv);    // = fl(t - 2*dot), matches numpy
                if (lq == 0) {
                    candsc[ci] = d;
                    atomicMin(&bestd[row_local], __float_as_uint(d));  // d>0: uint-monotone
                }
            } else if (lq == 0) {
                candsc[ci] = INFINITY;             // can't match bestd in phase 2
            }
        }
    }
    __syncthreads();
    for (int ci = t; ci < n; ci += TPB) {          // tie-break: lowest code at min d
        const unsigned uc = cand[ci];
        if (__float_as_uint(candsc[ci]) == bestd[uc >> 10])
            atomicMin(&bestc[uc >> 10], uc & 1023u);
    }
    __syncthreads();
    if (t < BM) out[IDX_OFF + r0 + t] = (float)bestc[t];

    // ---- st = q (r12-validated, |err| <= 6e-7 << thr): pure q-write ----
    {
        float4* out4 = (float4*)(out + (size_t)r0 * D);
        const float4* emb4 = (const float4*)emb;
        #pragma unroll
        for (int i = 0; i < (BM * D) / (4 * TPB); ++i) {   // 16 iters
            const int e = i * TPB + t;
            out4[e] = emb4[((size_t)bestc[e >> 6] << 6) + (e & 63)];
        }
    }

    // ---- loss partial: sum of winner distances (bestd) in f64, fixed tree ----
    if (t < 64) {
        double s = (double)__uint_as_float(bestd[t]);
        #pragma unroll
        for (int m = 1; m < 64; m <<= 1) s += __shfl_xor(s, m);
        if (t == 0) lsum[blockIdx.x] = s;
    }
}

// fin: loss = 1.25 * sum(d_winner) / (N*D); one wave, fixed-tree reduction
__global__ void fin_kernel(const double* __restrict__ lsum, float* __restrict__ out) {
    const int l = threadIdx.x;                     // 64 lanes
    double s = 0.0;
    #pragma unroll
    for (int i = 0; i < NBLK / 64; ++i) s += lsum[l * (NBLK / 64) + i];
    #pragma unroll
    for (int m = 1; m < 64; m <<= 1) s += __shfl_xor(s, m);
    if (l == 0) out[LOSS_OFF] = (float)(1.25 * s / (double)ST_SIZE);
}

extern "C" void kernel_launch(void* const* d_in, const int* in_sizes, int n_in,
                              void* d_out, int out_size, void* d_ws, size_t ws_size,
                              hipStream_t stream) {
    const float* inp = (const float*)d_in[0];
    const float* emb = (const float*)d_in[1];
    float* out = (float*)d_out;
    unsigned short* pb = (unsigned short*)d_ws;               // 512 KB (frag-ordered bf16)
    float*  se_ws      = (float*)((char*)d_ws + 524288);      //   4 KB
    double* lsum       = (double*)((char*)d_ws + 528384);     //   8 KB (1024 doubles)

    prep_kernel<<<132, 256, 0, stream>>>(emb, pb, se_ws);
    vq_main<<<NBLK, TPB, 0, stream>>>(inp, emb, pb, se_ws, out, lsum);
    fin_kernel<<<1, 64, 0, stream>>>(lsum, out);
}

// Round 20
// 157.316 us; speedup vs baseline: 4.6881x; 1.1069x over previous
//
#include <hip/hip_runtime.h>
#include <math.h>

#define D 256
#define K 1024
#define NR 65536
#define ST_SIZE (NR * D)          // 16777216
#define LOSS_OFF ST_SIZE
#define IDX_OFF (ST_SIZE + 1)
#define BM 64
#define TPB 256
#define NRND 64                   // staging rounds, one 16-code tile each
#define NBLK (NR / BM)            // 1024
#define MARGIN 2e-3f
#define CAND_CAP 1536

typedef short bf16x8 __attribute__((ext_vector_type(8)));
typedef float f32x4 __attribute__((ext_vector_type(4)));

// async global->LDS, 16B per lane; LDS dest = wave-uniform base + lane*16
#define GLDS(g, s) __builtin_amdgcn_global_load_lds( \
    (const __attribute__((address_space(1))) unsigned int*)(g), \
    (__attribute__((address_space(3))) unsigned int*)(s), 16, 0, 0)

// f32 -> bf16 RNE (bit-level)
__device__ __forceinline__ unsigned f2bf(float f) {
    unsigned u = __float_as_uint(f);
    return (u + 0x7FFFu + ((u >> 16) & 1u)) >> 16;
}
__device__ __forceinline__ uint4 packB(float4 a, float4 b) {
    uint4 w;
    w.x = f2bf(-2.f * a.x) | (f2bf(-2.f * a.y) << 16);
    w.y = f2bf(-2.f * a.z) | (f2bf(-2.f * a.w) << 16);
    w.z = f2bf(-2.f * b.x) | (f2bf(-2.f * b.y) << 16);
    w.w = f2bf(-2.f * b.z) | (f2bf(-2.f * b.w) << 16);
    return w;
}

// anti-contraction square (numpy-identical rounding: mul rounded alone)
__device__ __forceinline__ float sq_nf(float x) {
    float s = x * x;
    asm volatile("" : "+v"(s));
    return s;
}
// numpy pairwise sum of squares over 256 elements (bit-exact, validated r2-r19)
template <typename F>
__device__ __forceinline__ float np_sumsq256(F ld) {
    float tot[2];
    #pragma unroll
    for (int h = 0; h < 2; ++h) {
        const int base = h * 128;
        float r[8];
        #pragma unroll
        for (int j = 0; j < 8; ++j) r[j] = sq_nf(ld(base + j));
        for (int i = 8; i < 128; i += 8) {
            #pragma unroll
            for (int j = 0; j < 8; ++j) r[j] += sq_nf(ld(base + i + j));
        }
        tot[h] = ((r[0] + r[1]) + (r[2] + r[3])) + ((r[4] + r[5]) + (r[6] + r[7]));
    }
    return tot[0] + tot[1];
}

// prep: blocks 0..127 pack bf16(-2e) in 16x16x32 B-fragment order (r18/r19-proven)
//   chunk ci = (ct*8 + kb)*64 + l : lane l holds -2*e[ct*16+(l&15)][kb*32+(l>>4)*8 + j]
__global__ void prep_kernel(const float* __restrict__ emb,
                            unsigned short* __restrict__ pb,
                            float* __restrict__ se) {
    if (blockIdx.x < 128) {
        const int c  = blockIdx.x * 256 + threadIdx.x;    // chunk id, 32768 total
        const int ct = c >> 9;                            // 16-code tile 0..63
        const int r  = c & 511;
        const int kb = r >> 6, l = r & 63;
        const float* srcp = emb + (size_t)(ct * 16 + (l & 15)) * D
                                + kb * 32 + (l >> 4) * 8;
        const float4* s4 = (const float4*)srcp;
        ((uint4*)pb)[c] = packB(s4[0], s4[1]);
    } else {
        const int k = (blockIdx.x - 128) * 256 + threadIdx.x;   // < 1024
        const float* row = emb + (size_t)k * D;
        se[k] = np_sumsq256([&](int i) { return row[i]; });
    }
}

// main: r19 engine with ~30 KB LDS -> 4-5 blocks/CU (the occupancy lever)
__global__ __attribute__((amdgpu_waves_per_eu(2, 4))) __launch_bounds__(TPB)
void vq_main(const float* __restrict__ inp, const float* __restrict__ emb,
             const unsigned short* __restrict__ pb, const float* __restrict__ se,
             float* __restrict__ out, double* __restrict__ lsum) {
    __shared__ __align__(16) unsigned short Bt[2][4096];   // 2 x 8 KB dbuf
    __shared__ float sx_s[BM];                             // .25 KB
    __shared__ float rfin[BM];                             // .25 KB
    __shared__ unsigned cand[CAND_CAP];                    //  6 KB
    __shared__ float candsc[CAND_CAP];                     //  6 KB
    __shared__ unsigned bestd[BM];                         // .25 KB
    __shared__ unsigned bestc[BM];                         // .25 KB (~29.8 KB tot)
    __shared__ int ncand;

    const int t   = threadIdx.x;
    const int ws  = t >> 6;      // wave 0..3: rows ws*16 .. ws*16+15
    const int l   = t & 63;
    const int c16 = l & 15;      // A-row / B-col lane index
    const int g4  = l >> 4;      // k-group 0..3
    const int r0  = blockIdx.x * BM;

    if (t < BM) { bestd[t] = 0xFFFFFFFFu; bestc[t] = 0xFFFFFFFFu; }
    if (t == 0) ncand = 0;

    // ---- A fragments (32 VGPR): row r0+ws*16+c16, k = kb*32 + g4*8 + j ----
    bf16x8 afr[8];
    {
        const float* xrow = inp + (size_t)(r0 + ws * 16 + c16) * D;
        #pragma unroll
        for (int kb = 0; kb < 8; ++kb) {
            const float4* p4 = (const float4*)(xrow + kb * 32 + g4 * 8);
            float4 a = p4[0], b = p4[1];
            bf16x8 v;
            v[0] = (short)f2bf(a.x); v[1] = (short)f2bf(a.y);
            v[2] = (short)f2bf(a.z); v[3] = (short)f2bf(a.w);
            v[4] = (short)f2bf(b.x); v[5] = (short)f2bf(b.y);
            v[6] = (short)f2bf(b.z); v[7] = (short)f2bf(b.w);
            afr[kb] = v;
        }
    }

    // ---- fused sx: numpy-pairwise-exact, 16 lanes per row (pure shfl) ----
    {
        const int slot = t & 15, grp = t >> 4;   // 16 groups x 4 rows
        const int j = slot & 7, h = slot >> 3;
        #pragma unroll
        for (int p = 0; p < 4; ++p) {
            const int row = p * 16 + grp;
            const float* base = inp + (size_t)(r0 + row) * D + h * 128 + j;
            float s = sq_nf(base[0]);
            #pragma unroll
            for (int i = 1; i < 16; ++i) s += sq_nf(base[i * 8]);
            #pragma unroll
            for (int m = 1; m <= 8; m <<= 1) s += __shfl_xor(s, m);  // local-left
            if (slot == 0) sx_s[row] = s;
        }
    }

    float rmin[4];
    #pragma unroll
    for (int i = 0; i < 4; ++i) rmin[i] = INFINITY;

    const uint4* srcv = (const uint4*)pb;

    // async stage of round cr (one 16-code tile, 512 chunks x 16B) into buf
    auto stage = [&](int buf, int cr) {
        const uint4* g = srcv + (size_t)cr * 512;
        #pragma unroll
        for (int q = 0; q < 2; ++q) {
            char* lbase = (char*)&Bt[buf][0] + (q * 256 + ws * 64) * 16;  // wave-uniform
            GLDS(g + q * TPB + t, lbase);                                  // lane adds l*16
        }
    };

    stage(0, 0);
    int cur = 0;
    // ---- single sweep: 64 rounds x 8 MFMA; ONE barrier per round;
    //      next round's DMA flies under this round's MFMAs ----
    for (int cr = 0; cr < NRND; ++cr) {
        __syncthreads();                       // own DMA drained + all waves done prev
        if (cr + 1 < NRND) stage(cur ^ 1, cr + 1);
        const bf16x8* bch = (const bf16x8*)&Bt[cur][0];
        f32x4 acc;
        {
            const float sev = se[cr * 16 + c16];   // L2-resident (4 KB table)
            #pragma unroll
            for (int i = 0; i < 4; ++i) acc[i] = sev;
        }
        #pragma unroll
        for (int kb = 0; kb < 8; ++kb)
            acc = __builtin_amdgcn_mfma_f32_16x16x32_bf16(afr[kb], bch[kb * 64 + l], acc, 0, 0, 0);

        // running row-min: lane-local always; 16-lane butterfly every 2nd round
        // (staleness only raises threshold => flag set SUPERSET => argmin kept)
        #pragma unroll
        for (int i = 0; i < 4; ++i) rmin[i] = fminf(rmin[i], acc[i]);
        if ((cr & 1) == 0) {
            #pragma unroll
            for (int i = 0; i < 4; ++i) {
                #pragma unroll
                for (int m = 1; m <= 8; m <<= 1)
                    rmin[i] = fminf(rmin[i], __shfl_xor(rmin[i], m));
            }
        }
        #pragma unroll
        for (int i = 0; i < 4; ++i) {
            if (acc[i] <= rmin[i] + MARGIN) {
                const int row_local = ws * 16 + g4 * 4 + i;
                const int p = atomicAdd(&ncand, 1);
                if (p < CAND_CAP) {
                    cand[p]   = ((unsigned)row_local << 10) | (unsigned)(cr * 16 + c16);
                    candsc[p] = acc[i];
                }
            }
        }
        cur ^= 1;
    }
    // final butterfly -> exact per-row approx-min; publish for the filter
    #pragma unroll
    for (int i = 0; i < 4; ++i) {
        #pragma unroll
        for (int m = 1; m <= 8; m <<= 1)
            rmin[i] = fminf(rmin[i], __shfl_xor(rmin[i], m));
    }
    if (c16 == 0) {
        #pragma unroll
        for (int i = 0; i < 4; ++i)
            rfin[ws * 16 + g4 * 4 + i] = rmin[i];
    }
    __syncthreads();                               // cand list + rfin complete

    // ---- filter + exact f32 rescore: 16 lanes per candidate (proven) ----
    int n = ncand; if (n > CAND_CAP) n = CAND_CAP;
    {
        const int qw = l >> 4, lq = l & 15;        // quarter-wave, lane-in-quarter
        for (int ci = ws * 4 + qw; ci < n; ci += 16) {
            const unsigned uc = cand[ci];
            const int row_local = uc >> 10, code = uc & 1023;
            const float sc = candsc[ci];
            if (sc <= rfin[row_local] + MARGIN) {  // survives final-min filter
                const float4* xp = (const float4*)(inp + (size_t)(r0 + row_local) * D) + lq * 4;
                const float4* ep = (const float4*)(emb + (size_t)code * D) + lq * 4;
                float p = 0.f;
                #pragma unroll
                for (int q = 0; q < 4; ++q) {
                    float4 x = xp[q], e = ep[q];
                    p = fmaf(x.x, e.x, p);
                    p = fmaf(x.y, e.y, p);
                    p = fmaf(x.z, e.z, p);
                    p = fmaf(x.w, e.w, p);
                }
                #pragma unroll
                for (int m = 1; m <= 8; m <<= 1) p += __shfl_xor(p, m);
                const float tv = sx_s[row_local] + se[code];
                const float d  = fmaf(-2.f, p, tv);    // = fl(t - 2*dot), matches numpy
                if (lq == 0) {
                    candsc[ci] = d;
                    atomicMin(&bestd[row_local], __float_as_uint(d));  // d>0: uint-monotone
                }
            } else if (lq == 0) {
                candsc[ci] = INFINITY;             // can't match bestd in phase 2
            }
        }
    }
    __syncthreads();
    for (int ci = t; ci < n; ci += TPB) {          // tie-break: lowest code at min d
        const unsigned uc = cand[ci];
        if (__float_as_uint(candsc[ci]) == bestd[uc >> 10])
            atomicMin(&bestc[uc >> 10], uc & 1023u);
    }
    __syncthreads();
    if (t < BM) out[IDX_OFF + r0 + t] = (float)bestc[t];

    // ---- st = q (r12-validated, |err| <= 6e-7 << thr): pure q-write ----
    {
        float4* out4 = (float4*)(out + (size_t)r0 * D);
        const float4* emb4 = (const float4*)emb;
        #pragma unroll
        for (int i = 0; i < (BM * D) / (4 * TPB); ++i) {   // 16 iters
            const int e = i * TPB + t;
            out4[e] = emb4[((size_t)bestc[e >> 6] << 6) + (e & 63)];
        }
    }

    // ---- loss partial: sum of winner distances (bestd) in f64, fixed tree ----
    if (t < 64) {
        double s = (double)__uint_as_float(bestd[t]);
        #pragma unroll
        for (int m = 1; m < 64; m <<= 1) s += __shfl_xor(s, m);
        if (t == 0) lsum[blockIdx.x] = s;
    }
}

// fin: loss = 1.25 * sum(d_winner) / (N*D); one wave, fixed-tree reduction
__global__ void fin_kernel(const double* __restrict__ lsum, float* __restrict__ out) {
    const int l = threadIdx.x;                     // 64 lanes
    double s = 0.0;
    #pragma unroll
    for (int i = 0; i < NBLK / 64; ++i) s += lsum[l * (NBLK / 64) + i];
    #pragma unroll
    for (int m = 1; m < 64; m <<= 1) s += __shfl_xor(s, m);
    if (l == 0) out[LOSS_OFF] = (float)(1.25 * s / (double)ST_SIZE);
}

extern "C" void kernel_launch(void* const* d_in, const int* in_sizes, int n_in,
                              void* d_out, int out_size, void* d_ws, size_t ws_size,
                              hipStream_t stream) {
    const float* inp = (const float*)d_in[0];
    const float* emb = (const float*)d_in[1];
    float* out = (float*)d_out;
    unsigned short* pb = (unsigned short*)d_ws;               // 512 KB (frag-ordered bf16)
    float*  se_ws      = (float*)((char*)d_ws + 524288);      //   4 KB
    double* lsum       = (double*)((char*)d_ws + 528384);     //   8 KB (1024 doubles)

    prep_kernel<<<132, 256, 0, stream>>>(emb, pb, se_ws);
    vq_main<<<NBLK, TPB, 0, stream>>>(inp, emb, pb, se_ws, out, lsum);
    fin_kernel<<<1, 64, 0, stream>>>(lsum, out);
}

// Round 21
// 142.108 us; speedup vs baseline: 5.1898x; 1.1070x over previous
//
#include <hip/hip_runtime.h>
#include <math.h>

#define D 256
#define K 1024
#define NR 65536
#define ST_SIZE (NR * D)          // 16777216
#define LOSS_OFF ST_SIZE
#define IDX_OFF (ST_SIZE + 1)
#define BM 128
#define TPB 512
#define NRND 32                   // rounds, two 16-code tiles each
#define NBLK (NR / BM)            // 512
#define MARGIN 2e-3f
#define CAND_CAP 3072

typedef short bf16x8 __attribute__((ext_vector_type(8)));
typedef float f32x4 __attribute__((ext_vector_type(4)));

// async global->LDS, 16B per lane; LDS dest = wave-uniform base + lane*16
#define GLDS(g, s) __builtin_amdgcn_global_load_lds( \
    (const __attribute__((address_space(1))) unsigned int*)(g), \
    (__attribute__((address_space(3))) unsigned int*)(s), 16, 0, 0)

// f32 -> bf16 RNE (bit-level)
__device__ __forceinline__ unsigned f2bf(float f) {
    unsigned u = __float_as_uint(f);
    return (u + 0x7FFFu + ((u >> 16) & 1u)) >> 16;
}
__device__ __forceinline__ uint4 packB(float4 a, float4 b) {
    uint4 w;
    w.x = f2bf(-2.f * a.x) | (f2bf(-2.f * a.y) << 16);
    w.y = f2bf(-2.f * a.z) | (f2bf(-2.f * a.w) << 16);
    w.z = f2bf(-2.f * b.x) | (f2bf(-2.f * b.y) << 16);
    w.w = f2bf(-2.f * b.z) | (f2bf(-2.f * b.w) << 16);
    return w;
}

// anti-contraction square (numpy-identical rounding: mul rounded alone)
__device__ __forceinline__ float sq_nf(float x) {
    float s = x * x;
    asm volatile("" : "+v"(s));
    return s;
}
// numpy pairwise sum of squares over 256 elements (bit-exact, validated r2-r20)
template <typename F>
__device__ __forceinline__ float np_sumsq256(F ld) {
    float tot[2];
    #pragma unroll
    for (int h = 0; h < 2; ++h) {
        const int base = h * 128;
        float r[8];
        #pragma unroll
        for (int j = 0; j < 8; ++j) r[j] = sq_nf(ld(base + j));
        for (int i = 8; i < 128; i += 8) {
            #pragma unroll
            for (int j = 0; j < 8; ++j) r[j] += sq_nf(ld(base + i + j));
        }
        tot[h] = ((r[0] + r[1]) + (r[2] + r[3])) + ((r[4] + r[5]) + (r[6] + r[7]));
    }
    return tot[0] + tot[1];
}

// prep: blocks 0..127 pack bf16(-2e) in 16x16x32 B-fragment order (r18-r20 proven)
//   chunk ci = (ct*8 + kb)*64 + l : lane l holds -2*e[ct*16+(l&15)][kb*32+(l>>4)*8 + j]
__global__ void prep_kernel(const float* __restrict__ emb,
                            unsigned short* __restrict__ pb,
                            float* __restrict__ se) {
    if (blockIdx.x < 128) {
        const int c  = blockIdx.x * 256 + threadIdx.x;    // chunk id, 32768 total
        const int ct = c >> 9;                            // 16-code tile 0..63
        const int r  = c & 511;
        const int kb = r >> 6, l = r & 63;
        const float* srcp = emb + (size_t)(ct * 16 + (l & 15)) * D
                                + kb * 32 + (l >> 4) * 8;
        const float4* s4 = (const float4*)srcp;
        ((uint4*)pb)[c] = packB(s4[0], s4[1]);
    } else {
        const int k = (blockIdx.x - 128) * 256 + threadIdx.x;   // < 1024
        const float* row = emb + (size_t)k * D;
        se[k] = np_sumsq256([&](int i) { return row[i]; });
    }
}

// main: 8-wave BM=128, 32 rounds x {2 tiles, 4 indep MFMA chains}; 2 blocks/CU,
//       16 waves/CU; async GLDS dbuf; proven flag/rescore/select/epilogue
__global__ __attribute__((amdgpu_waves_per_eu(2, 4))) __launch_bounds__(TPB)
void vq_main(const float* __restrict__ inp, const float* __restrict__ emb,
             const unsigned short* __restrict__ pb, const float* __restrict__ se,
             float* __restrict__ out, double* __restrict__ lsum) {
    __shared__ __align__(16) unsigned short Bt[2][8192];   // 2 x 16 KB dbuf (2 tiles)
    __shared__ float sx_s[BM];                             // .5 KB
    __shared__ float rfin[BM];                             // .5 KB
    __shared__ unsigned cand[CAND_CAP];                    // 12 KB
    __shared__ float candsc[CAND_CAP];                     // 12 KB
    __shared__ unsigned bestd[BM];                         // .5 KB
    __shared__ unsigned bestc[BM];                         // .5 KB (~58 KB tot)
    __shared__ int ncand;

    const int t   = threadIdx.x;
    const int ws  = t >> 6;      // wave 0..7: rows ws*16 .. ws*16+15
    const int l   = t & 63;
    const int c16 = l & 15;      // A-row / B-col lane index
    const int g4  = l >> 4;      // k-group 0..3
    const int r0  = blockIdx.x * BM;

    if (t < BM) { bestd[t] = 0xFFFFFFFFu; bestc[t] = 0xFFFFFFFFu; }
    if (t == 0) ncand = 0;

    // ---- A fragments (32 VGPR): row r0+ws*16+c16, k = kb*32 + g4*8 + j ----
    bf16x8 afr[8];
    {
        const float* xrow = inp + (size_t)(r0 + ws * 16 + c16) * D;
        #pragma unroll
        for (int kb = 0; kb < 8; ++kb) {
            const float4* p4 = (const float4*)(xrow + kb * 32 + g4 * 8);
            float4 a = p4[0], b = p4[1];
            bf16x8 v;
            v[0] = (short)f2bf(a.x); v[1] = (short)f2bf(a.y);
            v[2] = (short)f2bf(a.z); v[3] = (short)f2bf(a.w);
            v[4] = (short)f2bf(b.x); v[5] = (short)f2bf(b.y);
            v[6] = (short)f2bf(b.z); v[7] = (short)f2bf(b.w);
            afr[kb] = v;
        }
    }

    // ---- fused sx: numpy-pairwise-exact, 16 lanes per row (pure shfl) ----
    {
        const int slot = t & 15, grp = t >> 4;   // 32 groups x 4 rows
        const int j = slot & 7, h = slot >> 3;
        #pragma unroll
        for (int p = 0; p < 4; ++p) {
            const int row = p * 32 + grp;
            const float* base = inp + (size_t)(r0 + row) * D + h * 128 + j;
            float s = sq_nf(base[0]);
            #pragma unroll
            for (int i = 1; i < 16; ++i) s += sq_nf(base[i * 8]);
            #pragma unroll
            for (int m = 1; m <= 8; m <<= 1) s += __shfl_xor(s, m);  // local-left
            if (slot == 0) sx_s[row] = s;
        }
    }

    float rmin[4];
    #pragma unroll
    for (int i = 0; i < 4; ++i) rmin[i] = INFINITY;

    const uint4* srcv = (const uint4*)pb;

    // async stage of round cr (two tiles = 1024 chunks x 16B) into buf
    auto stage = [&](int buf, int cr) {
        const uint4* g = srcv + (size_t)cr * 1024;
        #pragma unroll
        for (int q = 0; q < 2; ++q) {
            char* lbase = (char*)&Bt[buf][0] + (q * 512 + ws * 64) * 16;  // wave-uniform
            GLDS(g + q * TPB + t, lbase);                                  // lane adds l*16
        }
    };

    stage(0, 0);
    int cur = 0;
    // ---- single sweep: 32 rounds x {2 tiles x 8 MFMA, 4 indep chains};
    //      ONE barrier per round; next round's DMA flies under MFMAs ----
    for (int cr = 0; cr < NRND; ++cr) {
        __syncthreads();                       // own DMA drained + all waves done prev
        if (cr + 1 < NRND) stage(cur ^ 1, cr + 1);
        const bf16x8* bch = (const bf16x8*)&Bt[cur][0];
        f32x4 a0e, a0o, a1e, a1o;
        {
            const float sev0 = se[(cr * 2 + 0) * 16 + c16];   // L2-resident table
            const float sev1 = se[(cr * 2 + 1) * 16 + c16];
            #pragma unroll
            for (int i = 0; i < 4; ++i) { a0e[i] = sev0; a0o[i] = 0.f; a1e[i] = sev1; a1o[i] = 0.f; }
        }
        #pragma unroll
        for (int kb = 0; kb < 8; kb += 2) {    // 4 independent acc chains
            a0e = __builtin_amdgcn_mfma_f32_16x16x32_bf16(afr[kb],     bch[kb * 64 + l],             a0e, 0, 0, 0);
            a1e = __builtin_amdgcn_mfma_f32_16x16x32_bf16(afr[kb],     bch[512 + kb * 64 + l],       a1e, 0, 0, 0);
            a0o = __builtin_amdgcn_mfma_f32_16x16x32_bf16(afr[kb + 1], bch[(kb + 1) * 64 + l],       a0o, 0, 0, 0);
            a1o = __builtin_amdgcn_mfma_f32_16x16x32_bf16(afr[kb + 1], bch[512 + (kb + 1) * 64 + l], a1o, 0, 0, 0);
        }
        float sc0[4], sc1[4];
        #pragma unroll
        for (int i = 0; i < 4; ++i) { sc0[i] = a0e[i] + a0o[i]; sc1[i] = a1e[i] + a1o[i]; }

        // running row-min: lane-local always; 16-lane butterfly every 2nd round
        // (staleness only raises threshold => flag set SUPERSET => argmin kept)
        #pragma unroll
        for (int i = 0; i < 4; ++i) rmin[i] = fminf(rmin[i], fminf(sc0[i], sc1[i]));
        if ((cr & 1) == 0) {
            #pragma unroll
            for (int i = 0; i < 4; ++i) {
                #pragma unroll
                for (int m = 1; m <= 8; m <<= 1)
                    rmin[i] = fminf(rmin[i], __shfl_xor(rmin[i], m));
            }
        }
        #pragma unroll
        for (int i = 0; i < 4; ++i) {
            const int row_local = ws * 16 + g4 * 4 + i;
            if (sc0[i] <= rmin[i] + MARGIN) {
                const int p = atomicAdd(&ncand, 1);
                if (p < CAND_CAP) {
                    cand[p]   = ((unsigned)row_local << 10) | (unsigned)((cr * 2) * 16 + c16);
                    candsc[p] = sc0[i];
                }
            }
            if (sc1[i] <= rmin[i] + MARGIN) {
                const int p = atomicAdd(&ncand, 1);
                if (p < CAND_CAP) {
                    cand[p]   = ((unsigned)row_local << 10) | (unsigned)((cr * 2 + 1) * 16 + c16);
                    candsc[p] = sc1[i];
                }
            }
        }
        cur ^= 1;
    }
    // final butterfly -> exact per-row approx-min; publish for the filter
    #pragma unroll
    for (int i = 0; i < 4; ++i) {
        #pragma unroll
        for (int m = 1; m <= 8; m <<= 1)
            rmin[i] = fminf(rmin[i], __shfl_xor(rmin[i], m));
    }
    if (c16 == 0) {
        #pragma unroll
        for (int i = 0; i < 4; ++i)
            rfin[ws * 16 + g4 * 4 + i] = rmin[i];
    }
    __syncthreads();                               // cand list + rfin complete

    // ---- filter + exact f32 rescore: 16 lanes per candidate (proven) ----
    int n = ncand; if (n > CAND_CAP) n = CAND_CAP;
    {
        const int qw = l >> 4, lq = l & 15;        // quarter-wave, lane-in-quarter
        for (int ci = ws * 4 + qw; ci < n; ci += 32) {
            const unsigned uc = cand[ci];
            const int row_local = uc >> 10, code = uc & 1023;
            const float sc = candsc[ci];
            if (sc <= rfin[row_local] + MARGIN) {  // survives final-min filter
                const float4* xp = (const float4*)(inp + (size_t)(r0 + row_local) * D) + lq * 4;
                const float4* ep = (const float4*)(emb + (size_t)code * D) + lq * 4;
                float p = 0.f;
                #pragma unroll
                for (int q = 0; q < 4; ++q) {
                    float4 x = xp[q], e = ep[q];
                    p = fmaf(x.x, e.x, p);
                    p = fmaf(x.y, e.y, p);
                    p = fmaf(x.z, e.z, p);
                    p = fmaf(x.w, e.w, p);
                }
                #pragma unroll
                for (int m = 1; m <= 8; m <<= 1) p += __shfl_xor(p, m);
                const float tv = sx_s[row_local] + se[code];
                const float d  = fmaf(-2.f, p, tv);    // = fl(t - 2*dot), matches numpy
                if (lq == 0) {
                    candsc[ci] = d;
                    atomicMin(&bestd[row_local], __float_as_uint(d));  // d>0: uint-monotone
                }
            } else if (lq == 0) {
                candsc[ci] = INFINITY;             // can't match bestd in phase 2
            }
        }
    }
    __syncthreads();
    for (int ci = t; ci < n; ci += TPB) {          // tie-break: lowest code at min d
        const unsigned uc = cand[ci];
        if (__float_as_uint(candsc[ci]) == bestd[uc >> 10])
            atomicMin(&bestc[uc >> 10], uc & 1023u);
    }
    __syncthreads();
    if (t < BM) out[IDX_OFF + r0 + t] = (float)bestc[t];

    // ---- st = q (r12-validated, |err| <= 6e-7 << thr): pure q-write ----
    {
        float4* out4 = (float4*)(out + (size_t)r0 * D);
        const float4* emb4 = (const float4*)emb;
        #pragma unroll
        for (int i = 0; i < (BM * D) / (4 * TPB); ++i) {   // 16 iters
            const int e = i * TPB + t;
            out4[e] = emb4[((size_t)bestc[e >> 6] << 6) + (e & 63)];
        }
    }

    // ---- loss partial: sum of winner distances (bestd) in f64, fixed tree ----
    if (t < 64) {
        double s = (double)__uint_as_float(bestd[t]) + (double)__uint_as_float(bestd[t + 64]);
        #pragma unroll
        for (int m = 1; m < 64; m <<= 1) s += __shfl_xor(s, m);
        if (t == 0) lsum[blockIdx.x] = s;
    }
}

// fin: loss = 1.25 * sum(d_winner) / (N*D); one wave, fixed-tree reduction
__global__ void fin_kernel(const double* __restrict__ lsum, float* __restrict__ out) {
    const int l = threadIdx.x;                     // 64 lanes
    double s = 0.0;
    #pragma unroll
    for (int i = 0; i < NBLK / 64; ++i) s += lsum[l * (NBLK / 64) + i];
    #pragma unroll
    for (int m = 1; m < 64; m <<= 1) s += __shfl_xor(s, m);
    if (l == 0) out[LOSS_OFF] = (float)(1.25 * s / (double)ST_SIZE);
}

extern "C" void kernel_launch(void* const* d_in, const int* in_sizes, int n_in,
                              void* d_out, int out_size, void* d_ws, size_t ws_size,
                              hipStream_t stream) {
    const float* inp = (const float*)d_in[0];
    const float* emb = (const float*)d_in[1];
    float* out = (float*)d_out;
    unsigned short* pb = (unsigned short*)d_ws;               // 512 KB (frag-ordered bf16)
    float*  se_ws      = (float*)((char*)d_ws + 524288);      //   4 KB
    double* lsum       = (double*)((char*)d_ws + 528384);     //   4 KB (512 doubles)

    prep_kernel<<<132, 256, 0, stream>>>(emb, pb, se_ws);
    vq_main<<<NBLK, TPB, 0, stream>>>(inp, emb, pb, se_ws, out, lsum);
    fin_kernel<<<1, 64, 0, stream>>>(lsum, out);
}